// Round 1
// 1457.456 us; speedup vs baseline: 1.2544x; 1.2544x over previous
//
#include <hip/hip_runtime.h>
#include <hip/hip_bf16.h>
#include <math.h>

// ---------------- constants ----------------
#define WTOT 16810     // 2 batches * mper (41*41*5 = 8405)
#define MPER 8405
#define MAXROWS (WTOT * 48)

// meta layout (ints)
#define M_NKEPT 0
#define M_NWIN0 1      // 1,2,3
#define M_NWIN1 4      // 4,5,6
#define M_IS64  7
#define M_OFEAT 8
#define M_OCOOR 9
#define M_OBUF0 10     // 10,11,12
#define M_OMASK0 13    // 13,14,15
#define M_OBUF1 16     // 16,17,18
#define M_OMASK1 19    // 19,20,21
#define M_TOTAL 22
#define M_WORDS 64     // meta block size in ints (dict follows)

__device__ __forceinline__ int level_of(int c) {
    if (c < 16) return 0;
    if (c < 32) return 1;
    return 2;          // c < 100000 always here
}
__device__ __forceinline__ int target_of(int lvl) {
    return (lvl == 0) ? 16 : ((lvl == 1) ? 32 : 48);
}

// ---------------- scan helpers ----------------
__device__ __forceinline__ int wave_incl_scan(int v) {
#pragma unroll
    for (int o = 1; o < 64; o <<= 1) {
        int t = __shfl_up(v, o, 64);
        if ((int)(threadIdx.x & 63) >= o) v += t;
    }
    return v;
}

__device__ __forceinline__ int block_incl_scan_1024(int v, int* wsums, int* total) {
    int lane = threadIdx.x & 63, wid = threadIdx.x >> 6;
    int iv = wave_incl_scan(v);
    if (lane == 63) wsums[wid] = iv;
    __syncthreads();
    if (wid == 0) {
        int s = (lane < 16) ? wsums[lane] : 0;
        s = wave_incl_scan(s);
        if (lane < 16) wsums[lane] = s;
    }
    __syncthreads();
    int add = (wid > 0) ? wsums[wid - 1] : 0;
    int incl = iv + add;
    *total = wsums[15];
    __syncthreads();
    return incl;
}

// ---------------- kernels ----------------

__global__ void k_detect(const int* coors_i32, int* meta) {
    if (blockIdx.x == 0 && threadIdx.x == 0) {
        int nz = 0;
        for (int j = 0; j < 64; j++) nz += (coors_i32[2 * j + 1] != 0);
        meta[M_IS64] = (nz == 0) ? 1 : 0;
    }
}

// 400 window cells x 192 features: pe dictionary (bit-identical math to ref path)
__global__ void k_builddict(float* dict) {
    int j = threadIdx.x;           // 0..191
    int idx = blockIdx.x;          // 0..399 : idx = z + 4*y + 40*x
    int z = idx & 3;
    int y = (idx >> 2) % 10;
    int x = (idx >> 2) / 10;
    float zc = (float)z - 2.0f;
    float yc = (float)y - 5.0f;
    float xc = (float)x - 5.0f;
    int sel = j >> 6;
    float v = (sel == 0) ? xc : ((sel == 1) ? yc : zc);
    int kk = (j & 63) >> 1;
    float invf = (float)exp(6.907755278982137 * (double)kk / 32.0);  // 1000^(kk/32)
    float a = v / invf;
    dict[idx * 192 + j] = (j & 1) ? cosf(a) : sinf(a);
}

// window ids + in-window coords for both shifts; per-chunk histogram of bwi0
// histograms are TRANSPOSED: H[(window)*C + chunk]
__global__ void k_wincoords(const void* coors_raw, int N, int C,
                            int* bwi0, int* bwi1, int* ciw0, int* ciw1,
                            int* H0, const int* meta) {
    int i = blockIdx.x * blockDim.x + threadIdx.x;
    if (i >= N) return;
    int b, z, y, x;
    if (meta[M_IS64]) {
        const long long* c = (const long long*)coors_raw;
        long long o = 4LL * i;
        b = (int)c[o]; z = (int)c[o + 1]; y = (int)c[o + 2]; x = (int)c[o + 3];
    } else {
        const int* c = (const int*)coors_raw;
        b = c[4 * i]; z = c[4 * i + 1]; y = c[4 * i + 2]; x = c[4 * i + 3];
    }
    int chunk = i >> 10;
    {   // shift=false: shx=10, shy=10, shz=4
        int scx = x + 10, scy = y + 10, scz = z + 4;
        int w = b * MPER + (scx / 10) * 205 + (scy / 10) * 5 + (scz >> 2);
        bwi0[i] = w;
        ciw0[i] = (scz & 3) | ((scy % 10) << 8) | ((scx % 10) << 16);
        atomicAdd(&H0[(long long)w * C + chunk], 1);
    }
    {   // shift=true: shx=5, shy=5, shz=2
        int scx = x + 5, scy = y + 5, scz = z + 2;
        int w = b * MPER + (scx / 10) * 205 + (scy / 10) * 5 + (scz >> 2);
        bwi1[i] = w;
        ciw1[i] = (scz & 3) | ((scy % 10) << 8) | ((scx % 10) << 16);
    }
}

// wave-per-window exclusive prefix over chunks (transposed layout, coalesced)
__global__ __launch_bounds__(256) void k_prefix_t(int* H, int* counts, int C, int NW) {
    int w = (blockIdx.x * blockDim.x + threadIdx.x) >> 6;
    int lane = threadIdx.x & 63;
    if (w >= NW) return;
    long long base = (long long)w * C;
    int run = 0;
    for (int c0 = 0; c0 < C; c0 += 64) {
        int c = c0 + lane;
        int v = (c < C) ? H[base + c] : 0;
        int incl = wave_incl_scan(v);
        if (c < C) H[base + c] = run + incl - v;
        run += __shfl(incl, 63, 64);
    }
    if (lane == 0) counts[w] = run;
}

// stage1: inner rank in bwi0 (all voxels) -> keep0; histogram bwi1 over kept
__global__ __launch_bounds__(1024) void k_stage1(const int* bwi0, const int* bwi1,
        const int* counts0, const int* H0, int* H1, int* keep0, int N, int C) {
    __shared__ alignas(16) int swin[1024];
    int c = blockIdx.x, t = threadIdx.x;
    int i = (c << 10) + t;
    int w0 = (i < N) ? bwi0[i] : -1;
    swin[t] = w0;
    __syncthreads();
    if (i >= N) return;
    int local = 0;
    int jlim = ((t >> 6) + 1) << 6;
    const int4* s4 = (const int4*)swin;
    for (int j = 0; j < jlim; j += 4) {
        int4 q = s4[j >> 2];
        local += (q.x == w0 && j + 0 < t);
        local += (q.y == w0 && j + 1 < t);
        local += (q.z == w0 && j + 2 < t);
        local += (q.w == w0 && j + 3 < t);
    }
    int inner = H0[(long long)w0 * C + c] + local;
    int k0 = inner < target_of(level_of(counts0[w0]));
    keep0[i] = k0;
    if (k0) atomicAdd(&H1[(long long)bwi1[i] * C + c], 1);
}

// stage2: inner rank in bwi1 among keep0 -> keepf; histograms for final stage
__global__ __launch_bounds__(1024) void k_stage2(const int* bwi0, const int* bwi1,
        const int* keep0, const int* counts1k, const int* H1,
        int* HF0, int* HF1, int* keepf, int* chunkcnt, int N, int C) {
    __shared__ alignas(16) int swin[1024];
    __shared__ int blksum;
    int c = blockIdx.x, t = threadIdx.x;
    int i = (c << 10) + t;
    int k0 = (i < N) ? keep0[i] : 0;
    int w1 = k0 ? bwi1[i] : -1;
    swin[t] = w1;
    if (t == 0) blksum = 0;
    __syncthreads();
    int kf = 0;
    if (w1 >= 0) {
        int local = 0;
        int jlim = ((t >> 6) + 1) << 6;
        const int4* s4 = (const int4*)swin;
        for (int j = 0; j < jlim; j += 4) {
            int4 q = s4[j >> 2];
            local += (q.x == w1 && j + 0 < t);
            local += (q.y == w1 && j + 1 < t);
            local += (q.z == w1 && j + 2 < t);
            local += (q.w == w1 && j + 3 < t);
        }
        int inner1 = H1[(long long)w1 * C + c] + local;
        kf = inner1 < target_of(level_of(counts1k[w1]));
    }
    if (i < N) keepf[i] = kf;
    if (kf) {
        atomicAdd(&HF0[(long long)bwi0[i] * C + c], 1);
        atomicAdd(&HF1[(long long)w1 * C + c], 1);
    }
    unsigned long long b = __ballot(kf);
    if ((t & 63) == 0) atomicAdd(&blksum, __popcll(b));
    __syncthreads();
    if (t == 0) chunkcnt[c] = blksum;
}

// fused: block 0 = chunk-count scan (-> NKEPT); blocks 1,2 = conti for shift 0/1
__global__ __launch_bounds__(1024) void k_midscan(int* chunkcnt, int C, int* meta,
        const int* counts0, const int* fcount0, int* conti0,
        const int* counts1, const int* fcount1, int* conti1) {
    __shared__ int wsums[16];
    __shared__ int running;
    __shared__ int run3[3];
    if (blockIdx.x == 0) {
        if (threadIdx.x == 0) running = 0;
        __syncthreads();
        for (int base = 0; base < C; base += 1024) {
            int i = base + threadIdx.x;
            int v = (i < C) ? chunkcnt[i] : 0;
            int total;
            int incl = block_incl_scan_1024(v, wsums, &total);
            int run = running;
            if (i < C) chunkcnt[i] = run + incl - v;
            __syncthreads();
            if (threadIdx.x == 0) running = run + total;
            __syncthreads();
        }
        if (threadIdx.x == 0) meta[M_NKEPT] = running;
    } else {
        const int* counts = (blockIdx.x == 2) ? counts1 : counts0;
        const int* fcount = (blockIdx.x == 2) ? fcount1 : fcount0;
        int* conti = (blockIdx.x == 2) ? conti1 : conti0;
        int* nwin_out = meta + ((blockIdx.x == 2) ? M_NWIN1 : M_NWIN0);
        if (threadIdx.x < 3) run3[threadIdx.x] = 0;
        __syncthreads();
        for (int base = 0; base < WTOT; base += 1024) {
            int i = base + threadIdx.x;
            int c = (i < WTOT) ? counts[i] : 0;
            int f = (i < WTOT) ? fcount[i] : 0;
            int lvl = level_of(c);
            int act = (c > 0 && f > 0) ? 1 : 0;
            int packed = act ? (1 << (11 * lvl)) : 0;
            int total;
            int incl = block_incl_scan_1024(packed, wsums, &total);
            int excl = incl - packed;
            int r0 = run3[0], r1 = run3[1], r2 = run3[2];
            if (i < WTOT) {
                int e;
                if (lvl == 0) e = r0 + (excl & 2047);
                else if (lvl == 1) e = r1 + ((excl >> 11) & 2047);
                else e = r2 + ((excl >> 22) & 2047);
                conti[i] = e;
            }
            __syncthreads();
            if (threadIdx.x == 0) {
                run3[0] = r0 + (total & 2047);
                run3[1] = r1 + ((total >> 11) & 2047);
                run3[2] = r2 + ((total >> 22) & 2047);
            }
            __syncthreads();
        }
        if (threadIdx.x < 3) nwin_out[threadIdx.x] = run3[threadIdx.x];
    }
}

__global__ void k_meta(int* meta) {
    if (blockIdx.x || threadIdx.x) return;
    const int T[3] = {16, 32, 48};
    long long nk = meta[M_NKEPT];
    long long o = nk * 192;
    meta[M_OFEAT] = 0;
    meta[M_OCOOR] = (int)o;
    o += nk * 4;
    for (int d = 0; d < 3; d++) { meta[M_OBUF0 + d] = (int)o; o += (long long)meta[M_NWIN0 + d] * T[d] * 192; }
    for (int d = 0; d < 3; d++) { meta[M_OMASK0 + d] = (int)o; o += (long long)meta[M_NWIN0 + d] * T[d]; }
    for (int d = 0; d < 3; d++) { meta[M_OBUF1 + d] = (int)o; o += (long long)meta[M_NWIN1 + d] * T[d] * 192; }
    for (int d = 0; d < 3; d++) { meta[M_OMASK1 + d] = (int)o; o += (long long)meta[M_NWIN1 + d] * T[d]; }
    meta[M_TOTAL] = (int)o;
}

// stage3: final inner ranks + compaction index + row->ciw scatter
__global__ __launch_bounds__(1024) void k_stage3(const int* bwi0, const int* bwi1,
        const int* ciw0, const int* ciw1, const int* keepf,
        const int* counts0, const int* counts1k,
        const int* conti0, const int* conti1,
        const int* HF0, const int* HF1, const int* chunkpref,
        const int* meta, int* idxarr, int* rowvox0, int* rowvox1, int N, int C) {
    __shared__ alignas(16) int sw0[1024];
    __shared__ alignas(16) int sw1[1024];
    int c = blockIdx.x, t = threadIdx.x;
    int i = (c << 10) + t;
    int kf = (i < N) ? keepf[i] : 0;
    int w0 = kf ? bwi0[i] : -1;
    int w1 = kf ? bwi1[i] : -1;
    sw0[t] = w0;
    sw1[t] = w1;
    __syncthreads();
    if (!kf) return;
    int l0 = 0, l1 = 0, lk = 0;
    int jlim = ((t >> 6) + 1) << 6;
    const int4* a4 = (const int4*)sw0;
    const int4* b4 = (const int4*)sw1;
    for (int j = 0; j < jlim; j += 4) {
        int4 qa = a4[j >> 2];
        int4 qb = b4[j >> 2];
        int v0 = (j + 0 < t), v1 = (j + 1 < t), v2 = (j + 2 < t), v3 = (j + 3 < t);
        l0 += (qa.x == w0 && v0) + (qa.y == w0 && v1) + (qa.z == w0 && v2) + (qa.w == w0 && v3);
        lk += (qa.x != -1 && v0) + (qa.y != -1 && v1) + (qa.z != -1 && v2) + (qa.w != -1 && v3);
        l1 += (qb.x == w1 && v0) + (qb.y == w1 && v1) + (qb.z == w1 && v2) + (qb.w == w1 && v3);
    }
    int innerF0 = HF0[(long long)w0 * C + c] + l0;
    int innerF1 = HF1[(long long)w1 * C + c] + l1;
    int kpos = chunkpref[c] + lk;
    idxarr[kpos] = i;
    {
        int lvl = level_of(counts0[w0]);
        int T = target_of(lvl);
        int rb = (meta[M_OBUF0 + lvl] - meta[M_OBUF0]) / 192;
        rowvox0[rb + conti0[w0] * T + innerF0] = ciw0[i];
    }
    {
        int lvl = level_of(counts1k[w1]);
        int T = target_of(lvl);
        int rb = (meta[M_OBUF1 + lvl] - meta[M_OBUF1]) / 192;
        rowvox1[rb + conti1[w1] * T + innerF1] = ciw1[i];
    }
}

// gather features + coords for kept voxels; 4 rows per 256-thread block
__global__ __launch_bounds__(256) void k_renderA(const float* feats, const void* coors_raw,
                                                 const int* meta, const int* idxarr, float* out) {
    int nk = meta[M_NKEPT];
    int r = threadIdx.x >> 6, lane = threadIdx.x & 63;
    int k = blockIdx.x * 4 + r;
    if (k >= nk) return;
    int i = idxarr[k];
    const float4* src = (const float4*)(feats + (long long)i * 192);
    float4* dst = (float4*)(out + (long long)k * 192);
    if (lane < 48) {
        dst[lane] = src[lane];
    } else if (lane < 52) {
        int t = lane - 48;
        int v = meta[M_IS64] ? (int)((const long long*)coors_raw)[4LL * i + t]
                             : ((const int*)coors_raw)[4 * i + t];
        out[meta[M_OCOOR] + 4 * k + t] = (float)v;
    }
}

// write pe buffers + masks, each element exactly once; pe is a dict gather
__global__ __launch_bounds__(256) void k_renderB(const int* meta, const int* rowvox0,
                                                 const int* rowvox1, const float* dict,
                                                 float* out) {
    int obuf0 = meta[M_OBUF0], omask0 = meta[M_OMASK0];
    int obuf1 = meta[M_OBUF1], omask1 = meta[M_OMASK1];
    int ototal = meta[M_TOTAL];
    int step = gridDim.x * blockDim.x;
    for (int e = obuf0 + blockIdx.x * blockDim.x + threadIdx.x; e < ototal; e += step) {
        float val;
        bool pe0 = (e < omask0);
        bool pe1 = (e >= obuf1 && e < omask1);
        if (pe0 || pe1) {
            unsigned rel = (unsigned)(e - (pe1 ? obuf1 : obuf0));
            unsigned row = rel / 192u;
            unsigned j = rel - row * 192u;
            int ciw = pe1 ? rowvox1[row] : rowvox0[row];
            if (ciw < 0) {
                val = 0.0f;
            } else {
                int di = (ciw & 3) + ((ciw >> 8) & 15) * 4 + ((ciw >> 16) & 15) * 40;
                val = dict[di * 192 + (int)j];
            }
        } else {
            int r = e - ((e >= omask1) ? omask1 : omask0);
            int ciw = (e >= omask1) ? rowvox1[r] : rowvox0[r];
            val = (ciw < 0) ? 1.0f : 0.0f;
        }
        out[e] = val;
    }
}

// ---------------- host launch ----------------
extern "C" void kernel_launch(void* const* d_in, const int* in_sizes, int n_in,
                              void* d_out, int out_size, void* d_ws, size_t ws_size,
                              hipStream_t stream) {
    const float* feats = (const float*)d_in[0];
    const void* coors = d_in[1];
    int N = in_sizes[0] / 192;
    int C = (N + 1023) >> 10;

    int* I = (int*)d_ws;
    int* bwi0 = I;              int* bwi1 = bwi0 + N;
    int* ciw0 = bwi1 + N;       int* ciw1 = ciw0 + N;
    int* keep0 = ciw1 + N;      int* keepf = keep0 + N;
    int* idxarr = keepf + N;
    int* H0 = idxarr + N;                       // C*WTOT each, contiguous
    int* H1 = H0 + (long long)C * WTOT;
    int* HF0 = H1 + (long long)C * WTOT;
    int* HF1 = HF0 + (long long)C * WTOT;
    int* chunkcnt = HF1 + (long long)C * WTOT;  // C ints (zeroed with H block)
    int* counts0 = chunkcnt + C;
    int* counts1k = counts0 + WTOT;
    int* fcount0 = counts1k + WTOT;
    int* fcount1 = fcount0 + WTOT;              // contiguous after fcount0 (fused prefix)
    int* conti0 = fcount1 + WTOT;
    int* conti1 = conti0 + WTOT;
    int* rowvox0 = conti1 + WTOT;
    int* rowvox1 = rowvox0 + MAXROWS;
    int* meta = rowvox1 + MAXROWS;
    float* dict = (float*)(meta + M_WORDS);     // 400*192 floats

    int nb256 = (N + 255) / 256;
    int pbA = (WTOT + 3) / 4;         // wave-per-window prefix blocks
    int pbF = (2 * WTOT + 3) / 4;

    hipMemsetAsync(H0, 0, ((size_t)4 * C * WTOT + C) * sizeof(int), stream);
    hipMemsetAsync(rowvox0, 0xFF, (size_t)2 * MAXROWS * sizeof(int), stream);

    k_detect<<<1, 64, 0, stream>>>((const int*)coors, meta);
    k_builddict<<<400, 192, 0, stream>>>(dict);
    k_wincoords<<<nb256, 256, 0, stream>>>(coors, N, C, bwi0, bwi1, ciw0, ciw1, H0, meta);

    k_prefix_t<<<pbA, 256, 0, stream>>>(H0, counts0, C, WTOT);
    k_stage1<<<C, 1024, 0, stream>>>(bwi0, bwi1, counts0, H0, H1, keep0, N, C);

    k_prefix_t<<<pbA, 256, 0, stream>>>(H1, counts1k, C, WTOT);
    k_stage2<<<C, 1024, 0, stream>>>(bwi0, bwi1, keep0, counts1k, H1, HF0, HF1,
                                     keepf, chunkcnt, N, C);

    // HF0 and HF1 (and fcount0/fcount1) are contiguous: one fused prefix pass
    k_prefix_t<<<pbF, 256, 0, stream>>>(HF0, fcount0, C, 2 * WTOT);
    k_midscan<<<3, 1024, 0, stream>>>(chunkcnt, C, meta,
                                      counts0, fcount0, conti0,
                                      counts1k, fcount1, conti1);
    k_meta<<<1, 1, 0, stream>>>(meta);

    k_stage3<<<C, 1024, 0, stream>>>(bwi0, bwi1, ciw0, ciw1, keepf, counts0, counts1k,
                                     conti0, conti1, HF0, HF1, chunkcnt, meta,
                                     idxarr, rowvox0, rowvox1, N, C);

    k_renderA<<<(N + 3) / 4, 256, 0, stream>>>(feats, coors, meta, idxarr, (float*)d_out);
    k_renderB<<<2048, 256, 0, stream>>>(meta, rowvox0, rowvox1, dict, (float*)d_out);

    (void)n_in; (void)ws_size; (void)out_size;
}

// Round 2
// 1284.070 us; speedup vs baseline: 1.4237x; 1.1350x over previous
//
#include <hip/hip_runtime.h>
#include <math.h>

typedef unsigned int u32;
typedef unsigned short u16;

// ---------------- constants ----------------
#define WTOT 16810     // 2 batches * mper (41*41*5 = 8405)
#define MPER 8405
#define MAXROWS (WTOT * 48)

// meta layout (ints)
#define M_NKEPT 0
#define M_NWIN0 1      // 1,2,3
#define M_NWIN1 4      // 4,5,6
#define M_WORDS 16

__device__ __forceinline__ int level_of(int c) {
    if (c < 16) return 0;
    if (c < 32) return 1;
    return 2;
}
__device__ __forceinline__ int target_of(int lvl) {
    return (lvl == 0) ? 16 : ((lvl == 1) ? 32 : 48);
}

// ---------------- scan helpers ----------------
__device__ __forceinline__ int wave_incl_scan(int v) {
#pragma unroll
    for (int o = 1; o < 64; o <<= 1) {
        int t = __shfl_up(v, o, 64);
        if ((int)(threadIdx.x & 63) >= o) v += t;
    }
    return v;
}

__device__ __forceinline__ int block_incl_scan_1024(int v, int* wsums, int* total) {
    int lane = threadIdx.x & 63, wid = threadIdx.x >> 6;
    int iv = wave_incl_scan(v);
    if (lane == 63) wsums[wid] = iv;
    __syncthreads();
    if (wid == 0) {
        int s = (lane < 16) ? wsums[lane] : 0;
        s = wave_incl_scan(s);
        if (lane < 16) wsums[lane] = s;
    }
    __syncthreads();
    int add = (wid > 0) ? wsums[wid - 1] : 0;
    int incl = iv + add;
    *total = wsums[15];
    __syncthreads();
    return incl;
}

// inline is64 detection: first wave ballots high-halves of first 16 i64 coords
__device__ __forceinline__ int block_is64(const int* c32, int* sh) {
    if (threadIdx.x < 64) {
        unsigned long long b = __ballot(c32[2 * threadIdx.x + 1] != 0);
        if (threadIdx.x == 0) *sh = (b == 0ULL) ? 1 : 0;
    }
    __syncthreads();
    return *sh;
}

// ---------------- kernels ----------------

// voxel blocks: window ids + in-window coords + packed-pair histogram of bwi0
// extra blocks (>= NB): build the 400x192 pe dictionary (bit-identical math)
__global__ __launch_bounds__(256) void k_wincoords(const void* coors_raw, int N, int NB,
        int CE2, int* bwi0, int* bwi1, int* ciw0, int* ciw1, u32* H0, float* dict) {
    __shared__ int s64;
    if ((int)blockIdx.x >= NB) {
        int e = ((int)blockIdx.x - NB) * 256 + (int)threadIdx.x;
        if (e < 76800) {
            int idx = e / 192;
            int j = e - idx * 192;
            int dz = idx & 3;
            int dy = (idx >> 2) % 10;
            int dx = (idx >> 2) / 10;
            int sel = j >> 6;
            float v = (sel == 0) ? ((float)dx - 5.0f)
                    : ((sel == 1) ? ((float)dy - 5.0f) : ((float)dz - 2.0f));
            int kk = (j & 63) >> 1;
            float invf = (float)exp(6.907755278982137 * (double)kk / 32.0);  // 1000^(kk/32)
            float a = v / invf;
            dict[e] = (j & 1) ? cosf(a) : sinf(a);
        }
        return;
    }
    int is64 = block_is64((const int*)coors_raw, &s64);
    int i = (int)blockIdx.x * 256 + (int)threadIdx.x;
    if (i >= N) return;
    int b, z, y, x;
    if (is64) {
        const long long* c = (const long long*)coors_raw;
        long long o = 4LL * i;
        b = (int)c[o]; z = (int)c[o + 1]; y = (int)c[o + 2]; x = (int)c[o + 3];
    } else {
        const int* c = (const int*)coors_raw;
        b = c[4 * i]; z = c[4 * i + 1]; y = c[4 * i + 2]; x = c[4 * i + 3];
    }
    int ch = i >> 10;
    {   // shift=false: shx=10, shy=10, shz=4
        int scx = x + 10, scy = y + 10, scz = z + 4;
        int w = b * MPER + (scx / 10) * 205 + (scy / 10) * 5 + (scz >> 2);
        bwi0[i] = w;
        ciw0[i] = (scz & 3) | ((scy % 10) << 8) | ((scx % 10) << 16);
        atomicAdd(&H0[(size_t)w * CE2 + (ch >> 1)], 1u << ((ch & 1) * 16));
    }
    {   // shift=true: shx=5, shy=5, shz=2
        int scx = x + 5, scy = y + 5, scz = z + 2;
        int w = b * MPER + (scx / 10) * 205 + (scy / 10) * 5 + (scz >> 2);
        bwi1[i] = w;
        ciw1[i] = (scz & 3) | ((scy % 10) << 8) | ((scx % 10) << 16);
    }
}

// wave-per-window exclusive prefix over packed u16 chunk-pairs (in-place)
// writes saturated (<=1023) offsets; counts[w] = saturated window total
__global__ __launch_bounds__(256) void k_prefix16(u32* H, u16* counts, int CE2, int NW) {
    int w = ((int)blockIdx.x * 256 + (int)threadIdx.x) >> 6;
    int lane = threadIdx.x & 63;
    if (w >= NW) return;
    u32* row = H + (size_t)w * CE2;
    u32 run = 0;
    for (int p0 = 0; p0 < CE2; p0 += 64) {
        int p = p0 + lane;
        u32 v = (p < CE2) ? row[p] : 0u;
        u32 lo = v & 0xffffu, hi = v >> 16;
        int s = (int)(lo + hi);
        int incl = wave_incl_scan(s);
        u32 excl = (u32)(incl - s);
        u32 offlo = run + excl;
        u32 offhi = offlo + lo;
        if (offlo > 1023u) offlo = 1023u;
        if (offhi > 1023u) offhi = 1023u;
        if (p < CE2) row[p] = offlo | (offhi << 16);
        int tot = __shfl(incl, 63, 64);
        run += (u32)tot;
        if (run > 1023u) run = 1023u;
    }
    if (lane == 0) counts[w] = (u16)run;
}

// stage1: inner rank in bwi0 (all voxels) -> keep0; packed histogram of bwi1 over kept
__global__ __launch_bounds__(1024) void k_stage1(const int* bwi0, const int* bwi1,
        const u16* counts0, const u16* H0_16, u32* H1, int* keep0, int N, int CE, int CE2) {
    __shared__ alignas(16) int swin[1024];
    int c = blockIdx.x, t = threadIdx.x;
    int i = (c << 10) + t;
    int w0 = (i < N) ? bwi0[i] : -1;
    swin[t] = w0;
    __syncthreads();
    if (i >= N) return;
    int local = 0;
    int jlim = ((t >> 6) + 1) << 6;
    const int4* s4 = (const int4*)swin;
    for (int j = 0; j < jlim; j += 4) {
        int4 q = s4[j >> 2];
        local += (q.x == w0 && j + 0 < t);
        local += (q.y == w0 && j + 1 < t);
        local += (q.z == w0 && j + 2 < t);
        local += (q.w == w0 && j + 3 < t);
    }
    int inner = (int)H0_16[(size_t)w0 * CE + c] + local;
    int k0 = inner < target_of(level_of((int)counts0[w0]));
    keep0[i] = k0;
    if (k0) atomicAdd(&H1[(size_t)bwi1[i] * CE2 + (c >> 1)], 1u << ((c & 1) * 16));
}

// stage2: inner rank in bwi1 among keep0 -> keepf; packed histograms for final stage
__global__ __launch_bounds__(1024) void k_stage2(const int* bwi0, const int* bwi1,
        const int* keep0, const u16* counts1k, const u16* H1_16,
        u32* HF0, u32* HF1, int* keepf, int* chunkcnt, int N, int CE, int CE2) {
    __shared__ alignas(16) int swin[1024];
    __shared__ int blksum;
    int c = blockIdx.x, t = threadIdx.x;
    int i = (c << 10) + t;
    int k0 = (i < N) ? keep0[i] : 0;
    int w1 = k0 ? bwi1[i] : -1;
    swin[t] = w1;
    if (t == 0) blksum = 0;
    __syncthreads();
    int kf = 0;
    if (w1 >= 0) {
        int local = 0;
        int jlim = ((t >> 6) + 1) << 6;
        const int4* s4 = (const int4*)swin;
        for (int j = 0; j < jlim; j += 4) {
            int4 q = s4[j >> 2];
            local += (q.x == w1 && j + 0 < t);
            local += (q.y == w1 && j + 1 < t);
            local += (q.z == w1 && j + 2 < t);
            local += (q.w == w1 && j + 3 < t);
        }
        int inner1 = (int)H1_16[(size_t)w1 * CE + c] + local;
        kf = inner1 < target_of(level_of((int)counts1k[w1]));
    }
    if (i < N) keepf[i] = kf;
    if (kf) {
        int w0 = bwi0[i];
        atomicAdd(&HF0[(size_t)w0 * CE2 + (c >> 1)], 1u << ((c & 1) * 16));
        atomicAdd(&HF1[(size_t)w1 * CE2 + (c >> 1)], 1u << ((c & 1) * 16));
    }
    unsigned long long b = __ballot(kf);
    if ((t & 63) == 0) atomicAdd(&blksum, __popcll(b));
    __syncthreads();
    if (t == 0) chunkcnt[c] = blksum;
}

// fused: block 0 = chunk-count scan (-> NKEPT); blocks 1,2 = conti for shift 0/1
__global__ __launch_bounds__(1024) void k_midscan(int* chunkcnt, int C, int* meta,
        const u16* counts0, const u16* fcount0, int* conti0,
        const u16* counts1, const u16* fcount1, int* conti1) {
    __shared__ int wsums[16];
    __shared__ int running;
    __shared__ int run3[3];
    if (blockIdx.x == 0) {
        if (threadIdx.x == 0) running = 0;
        __syncthreads();
        for (int base = 0; base < C; base += 1024) {
            int i = base + threadIdx.x;
            int v = (i < C) ? chunkcnt[i] : 0;
            int total;
            int incl = block_incl_scan_1024(v, wsums, &total);
            int run = running;
            if (i < C) chunkcnt[i] = run + incl - v;
            __syncthreads();
            if (threadIdx.x == 0) running = run + total;
            __syncthreads();
        }
        if (threadIdx.x == 0) meta[M_NKEPT] = running;
    } else {
        const u16* counts = (blockIdx.x == 2) ? counts1 : counts0;
        const u16* fcount = (blockIdx.x == 2) ? fcount1 : fcount0;
        int* conti = (blockIdx.x == 2) ? conti1 : conti0;
        int* nwin_out = meta + ((blockIdx.x == 2) ? M_NWIN1 : M_NWIN0);
        if (threadIdx.x < 3) run3[threadIdx.x] = 0;
        __syncthreads();
        for (int base = 0; base < WTOT; base += 1024) {
            int i = base + threadIdx.x;
            int c = (i < WTOT) ? (int)counts[i] : 0;
            int f = (i < WTOT) ? (int)fcount[i] : 0;
            int lvl = level_of(c);
            int act = (c > 0 && f > 0) ? 1 : 0;
            int packed = act ? (1 << (11 * lvl)) : 0;
            int total;
            int incl = block_incl_scan_1024(packed, wsums, &total);
            int excl = incl - packed;
            int r0 = run3[0], r1 = run3[1], r2 = run3[2];
            if (i < WTOT) {
                int e;
                if (lvl == 0) e = r0 + (excl & 2047);
                else if (lvl == 1) e = r1 + ((excl >> 11) & 2047);
                else e = r2 + ((excl >> 22) & 2047);
                conti[i] = e;
            }
            __syncthreads();
            if (threadIdx.x == 0) {
                run3[0] = r0 + (total & 2047);
                run3[1] = r1 + ((total >> 11) & 2047);
                run3[2] = r2 + ((total >> 22) & 2047);
            }
            __syncthreads();
        }
        if (threadIdx.x < 3) nwin_out[threadIdx.x] = run3[threadIdx.x];
    }
}

// stage3: final inner ranks + compaction index + row->ciw scatter
__global__ __launch_bounds__(1024) void k_stage3(const int* bwi0, const int* bwi1,
        const int* ciw0, const int* ciw1, const int* keepf,
        const u16* counts0, const u16* counts1k,
        const int* conti0, const int* conti1,
        const u16* HF0_16, const u16* HF1_16, const int* chunkpref,
        const int* meta, int* idxarr, int* rowvox0, int* rowvox1, int N, int CE) {
    __shared__ alignas(16) int sw0[1024];
    __shared__ alignas(16) int sw1[1024];
    int c = blockIdx.x, t = threadIdx.x;
    int i = (c << 10) + t;
    int kf = (i < N) ? keepf[i] : 0;
    int w0 = kf ? bwi0[i] : -1;
    int w1 = kf ? bwi1[i] : -1;
    sw0[t] = w0;
    sw1[t] = w1;
    __syncthreads();
    if (!kf) return;
    int l0 = 0, l1 = 0, lk = 0;
    int jlim = ((t >> 6) + 1) << 6;
    const int4* a4 = (const int4*)sw0;
    const int4* b4 = (const int4*)sw1;
    for (int j = 0; j < jlim; j += 4) {
        int4 qa = a4[j >> 2];
        int4 qb = b4[j >> 2];
        int v0 = (j + 0 < t), v1 = (j + 1 < t), v2 = (j + 2 < t), v3 = (j + 3 < t);
        l0 += (qa.x == w0 && v0) + (qa.y == w0 && v1) + (qa.z == w0 && v2) + (qa.w == w0 && v3);
        lk += (qa.x != -1 && v0) + (qa.y != -1 && v1) + (qa.z != -1 && v2) + (qa.w != -1 && v3);
        l1 += (qb.x == w1 && v0) + (qb.y == w1 && v1) + (qb.z == w1 && v2) + (qb.w == w1 && v3);
    }
    int innerF0 = (int)HF0_16[(size_t)w0 * CE + c] + l0;
    int innerF1 = (int)HF1_16[(size_t)w1 * CE + c] + l1;
    int kpos = chunkpref[c] + lk;
    idxarr[kpos] = i;
    int n00 = meta[M_NWIN0], n01 = meta[M_NWIN0 + 1];
    int n10 = meta[M_NWIN1], n11 = meta[M_NWIN1 + 1];
    {
        int lvl = level_of((int)counts0[w0]);
        int T = target_of(lvl);
        int rb = (lvl == 0) ? 0 : ((lvl == 1) ? n00 * 16 : (n00 * 16 + n01 * 32));
        rowvox0[rb + conti0[w0] * T + innerF0] = ciw0[i];
    }
    {
        int lvl = level_of((int)counts1k[w1]);
        int T = target_of(lvl);
        int rb = (lvl == 0) ? 0 : ((lvl == 1) ? n10 * 16 : (n10 * 16 + n11 * 32));
        rowvox1[rb + conti1[w1] * T + innerF1] = ciw1[i];
    }
}

// fused render: blocks [0,NA) gather feats+coords; blocks [NA,grid) write pe+masks (float4)
__global__ __launch_bounds__(256) void k_render(const float* feats, const void* coors_raw,
        const int* meta, const int* idxarr, const int* rowvox0, const int* rowvox1,
        const float* dict, float* out, int NA) {
    __shared__ int s64;
    int nk = meta[M_NKEPT];
    int n00 = meta[M_NWIN0], n01 = meta[M_NWIN0 + 1], n02 = meta[M_NWIN0 + 2];
    int n10 = meta[M_NWIN1], n11 = meta[M_NWIN1 + 1], n12 = meta[M_NWIN1 + 2];
    int R0 = n00 * 16 + n01 * 32 + n02 * 48;
    int R1 = n10 * 16 + n11 * 32 + n12 * 48;
    int obuf0 = nk * 196;            // nk*192 feats + nk*4 coords
    int omask0 = obuf0 + R0 * 192;
    int obuf1 = omask0 + R0;
    int omask1 = obuf1 + R1 * 192;
    int ototal = omask1 + R1;
    if ((int)blockIdx.x < NA) {
        int is64 = block_is64((const int*)coors_raw, &s64);
        int ocoor = nk * 192;
        const float4* src = (const float4*)feats;
        float4* dst = (float4*)out;
        int tot = nk * 52;           // nk*48 feat-float4s + nk*4 coord scalars
        int step = NA * 256;
        for (int idx = (int)blockIdx.x * 256 + (int)threadIdx.x; idx < tot; idx += step) {
            if (idx < nk * 48) {
                int row = idx / 48;
                int col = idx - row * 48;
                dst[idx] = src[(size_t)idxarr[row] * 48 + col];
            } else {
                int cidx = idx - nk * 48;
                int k = cidx >> 2, tt = cidx & 3;
                int ii = idxarr[k];
                int v = is64 ? (int)((const long long*)coors_raw)[4LL * ii + tt]
                             : ((const int*)coors_raw)[4 * ii + tt];
                out[ocoor + cidx] = (float)v;
            }
        }
    } else {
        int q0 = obuf0 >> 2, q1 = ototal >> 2;
        const float4* dict4 = (const float4*)dict;
        float4* out4 = (float4*)out;
        int step = ((int)gridDim.x - NA) * 256;
        for (int q = q0 + ((int)blockIdx.x - NA) * 256 + (int)threadIdx.x; q < q1; q += step) {
            int e = q << 2;
            float4 val;
            bool pe1 = (e >= obuf1) && (e < omask1);
            if ((e < omask0) || pe1) {
                unsigned rel = (unsigned)(e - (pe1 ? obuf1 : obuf0));
                unsigned row = rel / 192u;
                unsigned j = rel - row * 192u;
                int ciw = pe1 ? rowvox1[row] : rowvox0[row];
                if (ciw < 0) {
                    val.x = val.y = val.z = val.w = 0.0f;
                } else {
                    int di = (ciw & 3) + ((ciw >> 8) & 15) * 4 + ((ciw >> 16) & 15) * 40;
                    val = dict4[di * 48 + (int)(j >> 2)];
                }
            } else {
                int base = (e >= omask1) ? omask1 : omask0;
                const int* rv = (e >= omask1) ? rowvox1 : rowvox0;
                int4 c4 = *(const int4*)(rv + (e - base));
                val.x = (c4.x < 0) ? 1.0f : 0.0f;
                val.y = (c4.y < 0) ? 1.0f : 0.0f;
                val.z = (c4.z < 0) ? 1.0f : 0.0f;
                val.w = (c4.w < 0) ? 1.0f : 0.0f;
            }
            out4[q] = val;
        }
    }
}

// ---------------- host launch ----------------
extern "C" void kernel_launch(void* const* d_in, const int* in_sizes, int n_in,
                              void* d_out, int out_size, void* d_ws, size_t ws_size,
                              hipStream_t stream) {
    const float* feats = (const float*)d_in[0];
    const void* coors = d_in[1];
    int N = in_sizes[0] / 192;
    int C = (N + 1023) >> 10;
    int CE = (C + 1) & ~1;          // pad chunks to even for u16-pair packing
    int CE2 = CE >> 1;
    size_t TW32 = (size_t)WTOT * CE2;   // u32 words per table
    int N4 = (N + 3) & ~3;

    u32* U = (u32*)d_ws;
    int* bwi0 = (int*)U;            int* bwi1 = bwi0 + N4;
    int* ciw0 = bwi1 + N4;          int* ciw1 = ciw0 + N4;
    int* keep0 = ciw1 + N4;         int* keepf = keep0 + N4;
    int* idxarr = keepf + N4;
    u32* H0 = (u32*)(idxarr + N4);  // 4 packed u16 tables, contiguous
    u32* H1 = H0 + TW32;
    u32* HF0 = H1 + TW32;
    u32* HF1 = HF0 + TW32;
    u16* counts0 = (u16*)(HF1 + TW32);          // u16[WTOT], padded to 8408 words
    u16* counts1k = (u16*)((u32*)counts0 + 8408);
    u16* fcount0 = (u16*)((u32*)counts1k + 8408);  // u16[2*WTOT] contiguous (dual prefix)
    u16* fcount1 = fcount0 + WTOT;
    int* chunkcnt = (int*)((u32*)fcount0 + 16812);
    int CP4 = (C + 3) & ~3;
    int* conti0 = chunkcnt + CP4;
    int* conti1 = conti0 + 16812;
    int* rowvox0 = conti1 + 16812;
    int* rowvox1 = rowvox0 + MAXROWS;
    int* meta = rowvox1 + MAXROWS;
    float* dict = (float*)(meta + M_WORDS);     // 400*192 floats

    int nb256 = (N + 255) / 256;

    hipMemsetAsync(H0, 0, 4 * TW32 * sizeof(u32), stream);
    hipMemsetAsync(rowvox0, 0xFF, (size_t)2 * MAXROWS * sizeof(int), stream);

    k_wincoords<<<nb256 + 300, 256, 0, stream>>>(coors, N, nb256, CE2,
                                                 bwi0, bwi1, ciw0, ciw1, H0, dict);

    int pgrid = (WTOT * 64 + 255) / 256;
    k_prefix16<<<pgrid, 256, 0, stream>>>(H0, counts0, CE2, WTOT);
    k_stage1<<<C, 1024, 0, stream>>>(bwi0, bwi1, counts0, (const u16*)H0, H1, keep0, N, CE, CE2);

    k_prefix16<<<pgrid, 256, 0, stream>>>(H1, counts1k, CE2, WTOT);
    k_stage2<<<C, 1024, 0, stream>>>(bwi0, bwi1, keep0, counts1k, (const u16*)H1,
                                     HF0, HF1, keepf, chunkcnt, N, CE, CE2);

    // HF0/HF1 rows are contiguous: one dual prefix pass writes fcount0 then fcount1
    k_prefix16<<<2 * pgrid, 256, 0, stream>>>(HF0, fcount0, CE2, 2 * WTOT);
    k_midscan<<<3, 1024, 0, stream>>>(chunkcnt, C, meta,
                                      counts0, fcount0, conti0,
                                      counts1k, fcount1, conti1);

    k_stage3<<<C, 1024, 0, stream>>>(bwi0, bwi1, ciw0, ciw1, keepf, counts0, counts1k,
                                     conti0, conti1, (const u16*)HF0, (const u16*)HF1,
                                     chunkcnt, meta, idxarr, rowvox0, rowvox1, N, CE);

    k_render<<<4096, 256, 0, stream>>>(feats, coors, meta, idxarr, rowvox0, rowvox1,
                                       dict, (float*)d_out, 1536);

    (void)n_in; (void)ws_size; (void)out_size;
}

// Round 3
// 1193.335 us; speedup vs baseline: 1.5320x; 1.0760x over previous
//
#include <hip/hip_runtime.h>
#include <math.h>

typedef unsigned int u32;
typedef unsigned short u16;
typedef __attribute__((ext_vector_type(4))) float f32x4;

// ---------------- constants ----------------
#define WTOT 16810     // 2 batches * mper (41*41*5 = 8405)
#define MPER 8405
#define MAXROWS (WTOT * 48)

// meta layout (ints)
#define M_NKEPT 0
#define M_NWIN0 1      // 1,2,3
#define M_NWIN1 4      // 4,5,6
#define M_WORDS 16

__device__ __forceinline__ int level_of(int c) {
    if (c < 16) return 0;
    if (c < 32) return 1;
    return 2;
}
__device__ __forceinline__ int target_of(int lvl) {
    return (lvl == 0) ? 16 : ((lvl == 1) ? 32 : 48);
}

// ---------------- scan helpers ----------------
__device__ __forceinline__ int wave_incl_scan(int v) {
#pragma unroll
    for (int o = 1; o < 64; o <<= 1) {
        int t = __shfl_up(v, o, 64);
        if ((int)(threadIdx.x & 63) >= o) v += t;
    }
    return v;
}

__device__ __forceinline__ int block_incl_scan_1024(int v, int* wsums, int* total) {
    int lane = threadIdx.x & 63, wid = threadIdx.x >> 6;
    int iv = wave_incl_scan(v);
    if (lane == 63) wsums[wid] = iv;
    __syncthreads();
    if (wid == 0) {
        int s = (lane < 16) ? wsums[lane] : 0;
        s = wave_incl_scan(s);
        if (lane < 16) wsums[lane] = s;
    }
    __syncthreads();
    int add = (wid > 0) ? wsums[wid - 1] : 0;
    int incl = iv + add;
    *total = wsums[15];
    __syncthreads();
    return incl;
}

// inline is64 detection: first wave ballots high-halves of first 16 i64 coords
__device__ __forceinline__ int block_is64(const int* c32, int* sh) {
    if (threadIdx.x < 64) {
        unsigned long long b = __ballot(c32[2 * threadIdx.x + 1] != 0);
        if (threadIdx.x == 0) *sh = (b == 0ULL) ? 1 : 0;
    }
    __syncthreads();
    return *sh;
}

// count same-key earlier-thread entries in a padded LDS list (uint4 sweep)
__device__ __forceinline__ int list_rank(const u32* list, int lcount, u32 key, int t) {
    int local = 0;
    int L4 = (lcount + 3) >> 2;
    const uint4* l4 = (const uint4*)list;
    for (int p = 0; p < L4; p++) {
        uint4 e = l4[p];
        local += ((e.x & ~1023u) == key && (int)(e.x & 1023u) < t);
        local += ((e.y & ~1023u) == key && (int)(e.y & 1023u) < t);
        local += ((e.z & ~1023u) == key && (int)(e.z & 1023u) < t);
        local += ((e.w & ~1023u) == key && (int)(e.w & 1023u) < t);
    }
    return local;
}

// ---------------- kernels ----------------

// voxel blocks: window ids + in-window coords + packed-pair histogram of bwi0
// extra blocks (>= NB): build the 400x192 pe dictionary (bit-identical math)
__global__ __launch_bounds__(256) void k_wincoords(const void* coors_raw, int N, int NB,
        int CE2, int* bwi0, int* bwi1, int* ciw0, int* ciw1, u32* H0, float* dict) {
    __shared__ int s64;
    if ((int)blockIdx.x >= NB) {
        int e = ((int)blockIdx.x - NB) * 256 + (int)threadIdx.x;
        if (e < 76800) {
            int idx = e / 192;
            int j = e - idx * 192;
            int dz = idx & 3;
            int dy = (idx >> 2) % 10;
            int dx = (idx >> 2) / 10;
            int sel = j >> 6;
            float v = (sel == 0) ? ((float)dx - 5.0f)
                    : ((sel == 1) ? ((float)dy - 5.0f) : ((float)dz - 2.0f));
            int kk = (j & 63) >> 1;
            float invf = (float)exp(6.907755278982137 * (double)kk / 32.0);  // 1000^(kk/32)
            float a = v / invf;
            dict[e] = (j & 1) ? cosf(a) : sinf(a);
        }
        return;
    }
    int is64 = block_is64((const int*)coors_raw, &s64);
    int i = (int)blockIdx.x * 256 + (int)threadIdx.x;
    if (i >= N) return;
    int b, z, y, x;
    if (is64) {
        const long long* c = (const long long*)coors_raw;
        long long o = 4LL * i;
        b = (int)c[o]; z = (int)c[o + 1]; y = (int)c[o + 2]; x = (int)c[o + 3];
    } else {
        const int* c = (const int*)coors_raw;
        b = c[4 * i]; z = c[4 * i + 1]; y = c[4 * i + 2]; x = c[4 * i + 3];
    }
    int ch = i >> 10;
    {   // shift=false: shx=10, shy=10, shz=4
        int scx = x + 10, scy = y + 10, scz = z + 4;
        int w = b * MPER + (scx / 10) * 205 + (scy / 10) * 5 + (scz >> 2);
        bwi0[i] = w;
        ciw0[i] = (scz & 3) | ((scy % 10) << 8) | ((scx % 10) << 16);
        atomicAdd(&H0[(size_t)w * CE2 + (ch >> 1)], 1u << ((ch & 1) * 16));
    }
    {   // shift=true: shx=5, shy=5, shz=2
        int scx = x + 5, scy = y + 5, scz = z + 2;
        int w = b * MPER + (scx / 10) * 205 + (scy / 10) * 5 + (scz >> 2);
        bwi1[i] = w;
        ciw1[i] = (scz & 3) | ((scy % 10) << 8) | ((scx % 10) << 16);
    }
}

// wave-per-window exclusive prefix over packed u16 chunk-pairs (in-place)
// writes saturated (<=1023) offsets; counts[w] = saturated window total
__global__ __launch_bounds__(256) void k_prefix16(u32* H, u16* counts, int CE2, int NW) {
    int w = ((int)blockIdx.x * 256 + (int)threadIdx.x) >> 6;
    int lane = threadIdx.x & 63;
    if (w >= NW) return;
    u32* row = H + (size_t)w * CE2;
    u32 run = 0;
    for (int p0 = 0; p0 < CE2; p0 += 64) {
        int p = p0 + lane;
        u32 v = (p < CE2) ? row[p] : 0u;
        u32 lo = v & 0xffffu, hi = v >> 16;
        int s = (int)(lo + hi);
        int incl = wave_incl_scan(s);
        u32 excl = (u32)(incl - s);
        u32 offlo = run + excl;
        u32 offhi = offlo + lo;
        if (offlo > 1023u) offlo = 1023u;
        if (offhi > 1023u) offhi = 1023u;
        if (p < CE2) row[p] = offlo | (offhi << 16);
        int tot = __shfl(incl, 63, 64);
        run += (u32)tot;
        if (run > 1023u) run = 1023u;
    }
    if (lane == 0) counts[w] = (u16)run;
}

// stage1: inner rank in bwi0 via collider-list -> keep0; packed histogram of bwi1 over kept
__global__ __launch_bounds__(1024) void k_stage1(const int* bwi0, const int* bwi1,
        const u16* counts0, const u16* H0_16, u32* H1, int* keep0, int N, int CE, int CE2) {
    __shared__ alignas(16) u32 list[1028];
    __shared__ int lcount;
    int c = blockIdx.x, t = threadIdx.x;
    int i = (c << 10) + t;
    if (t == 0) lcount = 0;
    __syncthreads();
    int w0 = -1, cur = 0, cnt = 0;
    if (i < N) {
        w0 = bwi0[i];
        size_t ro = (size_t)w0 * CE + c;
        cur = (int)H0_16[ro];
        int nxt = (c + 1 < CE) ? (int)H0_16[ro + 1] : (int)counts0[w0];
        cnt = nxt - cur;
        if (cnt >= 2) { int p = atomicAdd(&lcount, 1); list[p] = ((u32)w0 << 10) | (u32)t; }
    }
    __syncthreads();
    if (t < 3) list[lcount + t] = 0xFFFFFFFFu;
    __syncthreads();
    if (i >= N) return;
    int local = (cnt >= 2) ? list_rank(list, lcount, (u32)w0 << 10, t) : 0;
    int k0 = (cur + local) < target_of(level_of((int)counts0[w0]));
    keep0[i] = k0;
    if (k0) atomicAdd(&H1[(size_t)bwi1[i] * CE2 + (c >> 1)], 1u << ((c & 1) * 16));
}

// stage2: inner rank in bwi1 among keep0 via collider-list -> keepf; packed final histograms
__global__ __launch_bounds__(1024) void k_stage2(const int* bwi0, const int* bwi1,
        const int* keep0, const u16* counts1k, const u16* H1_16,
        u32* HF0, u32* HF1, int* keepf, int* chunkcnt, int N, int CE, int CE2) {
    __shared__ alignas(16) u32 list[1028];
    __shared__ int lcount, blksum;
    int c = blockIdx.x, t = threadIdx.x;
    int i = (c << 10) + t;
    int k0 = (i < N) ? keep0[i] : 0;
    if (t == 0) { lcount = 0; blksum = 0; }
    __syncthreads();
    int w1 = -1, cur = 0, cnt = 0;
    if (k0) {
        w1 = bwi1[i];
        size_t ro = (size_t)w1 * CE + c;
        cur = (int)H1_16[ro];
        int nxt = (c + 1 < CE) ? (int)H1_16[ro + 1] : (int)counts1k[w1];
        cnt = nxt - cur;
        if (cnt >= 2) { int p = atomicAdd(&lcount, 1); list[p] = ((u32)w1 << 10) | (u32)t; }
    }
    __syncthreads();
    if (t < 3) list[lcount + t] = 0xFFFFFFFFu;
    __syncthreads();
    int kf = 0;
    if (k0) {
        int local = (cnt >= 2) ? list_rank(list, lcount, (u32)w1 << 10, t) : 0;
        kf = (cur + local) < target_of(level_of((int)counts1k[w1]));
    }
    if (i < N) keepf[i] = kf;
    if (kf) {
        atomicAdd(&HF0[(size_t)bwi0[i] * CE2 + (c >> 1)], 1u << ((c & 1) * 16));
        atomicAdd(&HF1[(size_t)w1 * CE2 + (c >> 1)], 1u << ((c & 1) * 16));
    }
    unsigned long long b = __ballot(kf);
    if ((t & 63) == 0) atomicAdd(&blksum, __popcll(b));
    __syncthreads();
    if (t == 0) chunkcnt[c] = blksum;
}

// fused: block 0 = chunk-count scan (-> NKEPT); blocks 1,2 = conti for shift 0/1
__global__ __launch_bounds__(1024) void k_midscan(int* chunkcnt, int C, int* meta,
        const u16* counts0, const u16* fcount0, int* conti0,
        const u16* counts1, const u16* fcount1, int* conti1) {
    __shared__ int wsums[16];
    __shared__ int running;
    __shared__ int run3[3];
    if (blockIdx.x == 0) {
        if (threadIdx.x == 0) running = 0;
        __syncthreads();
        for (int base = 0; base < C; base += 1024) {
            int i = base + threadIdx.x;
            int v = (i < C) ? chunkcnt[i] : 0;
            int total;
            int incl = block_incl_scan_1024(v, wsums, &total);
            int run = running;
            if (i < C) chunkcnt[i] = run + incl - v;
            __syncthreads();
            if (threadIdx.x == 0) running = run + total;
            __syncthreads();
        }
        if (threadIdx.x == 0) meta[M_NKEPT] = running;
    } else {
        const u16* counts = (blockIdx.x == 2) ? counts1 : counts0;
        const u16* fcount = (blockIdx.x == 2) ? fcount1 : fcount0;
        int* conti = (blockIdx.x == 2) ? conti1 : conti0;
        int* nwin_out = meta + ((blockIdx.x == 2) ? M_NWIN1 : M_NWIN0);
        if (threadIdx.x < 3) run3[threadIdx.x] = 0;
        __syncthreads();
        for (int base = 0; base < WTOT; base += 1024) {
            int i = base + threadIdx.x;
            int c = (i < WTOT) ? (int)counts[i] : 0;
            int f = (i < WTOT) ? (int)fcount[i] : 0;
            int lvl = level_of(c);
            int act = (c > 0 && f > 0) ? 1 : 0;
            int packed = act ? (1 << (11 * lvl)) : 0;
            int total;
            int incl = block_incl_scan_1024(packed, wsums, &total);
            int excl = incl - packed;
            int r0 = run3[0], r1 = run3[1], r2 = run3[2];
            if (i < WTOT) {
                int e;
                if (lvl == 0) e = r0 + (excl & 2047);
                else if (lvl == 1) e = r1 + ((excl >> 11) & 2047);
                else e = r2 + ((excl >> 22) & 2047);
                conti[i] = e;
            }
            __syncthreads();
            if (threadIdx.x == 0) {
                run3[0] = r0 + (total & 2047);
                run3[1] = r1 + ((total >> 11) & 2047);
                run3[2] = r2 + ((total >> 22) & 2047);
            }
            __syncthreads();
        }
        if (threadIdx.x < 3) nwin_out[threadIdx.x] = run3[threadIdx.x];
    }
}

// stage3: final inner ranks via collider-lists + ballot compaction + row->ciw scatter
__global__ __launch_bounds__(1024) void k_stage3(const int* bwi0, const int* bwi1,
        const int* ciw0, const int* ciw1, const int* keepf,
        const u16* counts0, const u16* counts1k,
        const int* conti0, const int* conti1,
        const u16* HF0_16, const u16* HF1_16,
        const u16* fcount0, const u16* fcount1,
        const int* chunkpref, const int* meta,
        int* idxarr, int* rowvox0, int* rowvox1, int N, int CE) {
    __shared__ alignas(16) u32 list0[1028];
    __shared__ alignas(16) u32 list1[1028];
    __shared__ int lc0, lc1, wsum[16];
    int c = blockIdx.x, t = threadIdx.x, lane = t & 63, wv = t >> 6;
    int i = (c << 10) + t;
    if (t == 0) { lc0 = 0; lc1 = 0; }
    int kf = (i < N) ? keepf[i] : 0;
    unsigned long long m = __ballot(kf);
    if (lane == 0) wsum[wv] = __popcll(m);
    __syncthreads();
    if (t < 64) {
        int s = (t < 16) ? wsum[t] : 0;
        s = wave_incl_scan(s);
        if (t < 16) wsum[t] = s;
    }
    __syncthreads();
    int lk = (wv ? wsum[wv - 1] : 0) + __popcll(m & ((1ull << lane) - 1ull));
    int w0 = -1, w1 = -1, cur0 = 0, cur1 = 0, cnt0 = 0, cnt1 = 0;
    if (kf) {
        w0 = bwi0[i]; w1 = bwi1[i];
        size_t r0o = (size_t)w0 * CE + c;
        cur0 = (int)HF0_16[r0o];
        int nxt0 = (c + 1 < CE) ? (int)HF0_16[r0o + 1] : (int)fcount0[w0];
        cnt0 = nxt0 - cur0;
        if (cnt0 >= 2) { int p = atomicAdd(&lc0, 1); list0[p] = ((u32)w0 << 10) | (u32)t; }
        size_t r1o = (size_t)w1 * CE + c;
        cur1 = (int)HF1_16[r1o];
        int nxt1 = (c + 1 < CE) ? (int)HF1_16[r1o + 1] : (int)fcount1[w1];
        cnt1 = nxt1 - cur1;
        if (cnt1 >= 2) { int p = atomicAdd(&lc1, 1); list1[p] = ((u32)w1 << 10) | (u32)t; }
    }
    __syncthreads();
    if (t < 3) { list0[lc0 + t] = 0xFFFFFFFFu; list1[lc1 + t] = 0xFFFFFFFFu; }
    __syncthreads();
    if (!kf) return;
    int l0 = (cnt0 >= 2) ? list_rank(list0, lc0, (u32)w0 << 10, t) : 0;
    int l1 = (cnt1 >= 2) ? list_rank(list1, lc1, (u32)w1 << 10, t) : 0;
    int innerF0 = cur0 + l0;
    int innerF1 = cur1 + l1;
    idxarr[chunkpref[c] + lk] = i;
    int n00 = meta[M_NWIN0], n01 = meta[M_NWIN0 + 1];
    int n10 = meta[M_NWIN1], n11 = meta[M_NWIN1 + 1];
    {
        int lvl = level_of((int)counts0[w0]);
        int T = target_of(lvl);
        int rb = (lvl == 0) ? 0 : ((lvl == 1) ? n00 * 16 : (n00 * 16 + n01 * 32));
        rowvox0[rb + conti0[w0] * T + innerF0] = ciw0[i];
    }
    {
        int lvl = level_of((int)counts1k[w1]);
        int T = target_of(lvl);
        int rb = (lvl == 0) ? 0 : ((lvl == 1) ? n10 * 16 : (n10 * 16 + n11 * 32));
        rowvox1[rb + conti1[w1] * T + innerF1] = ciw1[i];
    }
}

// fused render: blocks [0,NA) gather feats+coords; blocks [NA,grid) write pe+masks
// all bulk output via non-temporal stores (write-once, never re-read)
__global__ __launch_bounds__(256) void k_render(const float* feats, const void* coors_raw,
        const int* meta, const int* idxarr, const int* rowvox0, const int* rowvox1,
        const float* dict, float* out, int NA) {
    __shared__ int s64;
    int nk = meta[M_NKEPT];
    int n00 = meta[M_NWIN0], n01 = meta[M_NWIN0 + 1], n02 = meta[M_NWIN0 + 2];
    int n10 = meta[M_NWIN1], n11 = meta[M_NWIN1 + 1], n12 = meta[M_NWIN1 + 2];
    int R0 = n00 * 16 + n01 * 32 + n02 * 48;
    int R1 = n10 * 16 + n11 * 32 + n12 * 48;
    int obuf0 = nk * 196;            // nk*192 feats + nk*4 coords
    int omask0 = obuf0 + R0 * 192;
    int obuf1 = omask0 + R0;
    int omask1 = obuf1 + R1 * 192;
    int ototal = omask1 + R1;
    if ((int)blockIdx.x < NA) {
        int is64 = block_is64((const int*)coors_raw, &s64);
        int ocoor = nk * 192;
        const f32x4* src = (const f32x4*)feats;
        f32x4* dst = (f32x4*)out;
        int tot = nk * 52;           // nk*48 feat-float4s + nk*4 coord scalars
        int step = NA * 256;
        for (int idx = (int)blockIdx.x * 256 + (int)threadIdx.x; idx < tot; idx += step) {
            if (idx < nk * 48) {
                int row = idx / 48;
                int col = idx - row * 48;
                f32x4 v = src[(size_t)idxarr[row] * 48 + col];
                __builtin_nontemporal_store(v, dst + idx);
            } else {
                int cidx = idx - nk * 48;
                int k = cidx >> 2, tt = cidx & 3;
                int ii = idxarr[k];
                int v = is64 ? (int)((const long long*)coors_raw)[4LL * ii + tt]
                             : ((const int*)coors_raw)[4 * ii + tt];
                out[ocoor + cidx] = (float)v;
            }
        }
    } else {
        int q0 = obuf0 >> 2, q1 = ototal >> 2;
        const f32x4* dict4 = (const f32x4*)dict;
        f32x4* out4 = (f32x4*)out;
        int step = ((int)gridDim.x - NA) * 256;
        for (int q = q0 + ((int)blockIdx.x - NA) * 256 + (int)threadIdx.x; q < q1; q += step) {
            int e = q << 2;
            f32x4 val;
            bool pe1 = (e >= obuf1) && (e < omask1);
            if ((e < omask0) || pe1) {
                unsigned rel = (unsigned)(e - (pe1 ? obuf1 : obuf0));
                unsigned row = rel / 192u;
                unsigned j = rel - row * 192u;
                int ciw = pe1 ? rowvox1[row] : rowvox0[row];
                if (ciw < 0) {
                    val = (f32x4){0.0f, 0.0f, 0.0f, 0.0f};
                } else {
                    int di = (ciw & 3) + ((ciw >> 8) & 15) * 4 + ((ciw >> 16) & 15) * 40;
                    val = dict4[di * 48 + (int)(j >> 2)];
                }
            } else {
                int base = (e >= omask1) ? omask1 : omask0;
                const int* rv = (e >= omask1) ? rowvox1 : rowvox0;
                int4 c4 = *(const int4*)(rv + (e - base));
                val.x = (c4.x < 0) ? 1.0f : 0.0f;
                val.y = (c4.y < 0) ? 1.0f : 0.0f;
                val.z = (c4.z < 0) ? 1.0f : 0.0f;
                val.w = (c4.w < 0) ? 1.0f : 0.0f;
            }
            __builtin_nontemporal_store(val, out4 + q);
        }
    }
}

// ---------------- host launch ----------------
extern "C" void kernel_launch(void* const* d_in, const int* in_sizes, int n_in,
                              void* d_out, int out_size, void* d_ws, size_t ws_size,
                              hipStream_t stream) {
    const float* feats = (const float*)d_in[0];
    const void* coors = d_in[1];
    int N = in_sizes[0] / 192;
    int C = (N + 1023) >> 10;
    int CE = (C + 1) & ~1;          // pad chunks to even for u16-pair packing
    int CE2 = CE >> 1;
    size_t TW32 = (size_t)WTOT * CE2;   // u32 words per table
    int N4 = (N + 3) & ~3;

    u32* U = (u32*)d_ws;
    int* bwi0 = (int*)U;            int* bwi1 = bwi0 + N4;
    int* ciw0 = bwi1 + N4;          int* ciw1 = ciw0 + N4;
    int* keep0 = ciw1 + N4;         int* keepf = keep0 + N4;
    int* idxarr = keepf + N4;
    u32* H0 = (u32*)(idxarr + N4);  // 4 packed u16 tables, contiguous
    u32* H1 = H0 + TW32;
    u32* HF0 = H1 + TW32;
    u32* HF1 = HF0 + TW32;
    u16* counts0 = (u16*)(HF1 + TW32);          // u16[WTOT], padded to 8408 words
    u16* counts1k = (u16*)((u32*)counts0 + 8408);
    u16* fcount0 = (u16*)((u32*)counts1k + 8408);  // u16[2*WTOT] contiguous (dual prefix)
    u16* fcount1 = fcount0 + WTOT;
    int* chunkcnt = (int*)((u32*)fcount0 + 16812);
    int CP4 = (C + 3) & ~3;
    int* conti0 = chunkcnt + CP4;
    int* conti1 = conti0 + 16812;
    int* rowvox0 = conti1 + 16812;
    int* rowvox1 = rowvox0 + MAXROWS;
    int* meta = rowvox1 + MAXROWS;
    float* dict = (float*)(meta + M_WORDS);     // 400*192 floats

    int nb256 = (N + 255) / 256;

    hipMemsetAsync(H0, 0, 4 * TW32 * sizeof(u32), stream);
    hipMemsetAsync(rowvox0, 0xFF, (size_t)2 * MAXROWS * sizeof(int), stream);

    k_wincoords<<<nb256 + 300, 256, 0, stream>>>(coors, N, nb256, CE2,
                                                 bwi0, bwi1, ciw0, ciw1, H0, dict);

    int pgrid = (WTOT * 64 + 255) / 256;
    k_prefix16<<<pgrid, 256, 0, stream>>>(H0, counts0, CE2, WTOT);
    k_stage1<<<C, 1024, 0, stream>>>(bwi0, bwi1, counts0, (const u16*)H0, H1, keep0, N, CE, CE2);

    k_prefix16<<<pgrid, 256, 0, stream>>>(H1, counts1k, CE2, WTOT);
    k_stage2<<<C, 1024, 0, stream>>>(bwi0, bwi1, keep0, counts1k, (const u16*)H1,
                                     HF0, HF1, keepf, chunkcnt, N, CE, CE2);

    // HF0/HF1 rows are contiguous: one dual prefix pass writes fcount0 then fcount1
    k_prefix16<<<2 * pgrid, 256, 0, stream>>>(HF0, fcount0, CE2, 2 * WTOT);
    k_midscan<<<3, 1024, 0, stream>>>(chunkcnt, C, meta,
                                      counts0, fcount0, conti0,
                                      counts1k, fcount1, conti1);

    k_stage3<<<C, 1024, 0, stream>>>(bwi0, bwi1, ciw0, ciw1, keepf, counts0, counts1k,
                                     conti0, conti1, (const u16*)HF0, (const u16*)HF1,
                                     fcount0, fcount1, chunkcnt, meta,
                                     idxarr, rowvox0, rowvox1, N, CE);

    k_render<<<4096, 256, 0, stream>>>(feats, coors, meta, idxarr, rowvox0, rowvox1,
                                       dict, (float*)d_out, 1536);

    (void)n_in; (void)ws_size; (void)out_size;
}

// Round 5
// 1158.056 us; speedup vs baseline: 1.5787x; 1.0305x over previous
//
#include <hip/hip_runtime.h>
#include <math.h>

typedef unsigned int u32;
typedef unsigned short u16;
typedef unsigned char u8;
typedef unsigned long long u64;
typedef __attribute__((ext_vector_type(4))) float f32x4;
typedef __attribute__((ext_vector_type(4))) int i32x4;

// ---------------- constants ----------------
#define WTOT 16810     // 2 batches * mper (41*41*5 = 8405)
#define MPER 8405
#define MAXROWS (WTOT * 48)

// meta layout (ints)
#define M_NKEPT 0
#define M_NWIN0 1      // 1,2,3
#define M_NWIN1 4      // 4,5,6
#define M_WORDS 16

__device__ __forceinline__ int level_of(int c) {
    if (c < 16) return 0;
    if (c < 32) return 1;
    return 2;
}
__device__ __forceinline__ int target_of(int lvl) {
    return (lvl == 0) ? 16 : ((lvl == 1) ? 32 : 48);
}

// ---------------- scan helpers ----------------
__device__ __forceinline__ int wave_incl_scan(int v) {
#pragma unroll
    for (int o = 1; o < 64; o <<= 1) {
        int t = __shfl_up(v, o, 64);
        if ((int)(threadIdx.x & 63) >= o) v += t;
    }
    return v;
}

__device__ __forceinline__ int block_incl_scan_1024(int v, int* wsums, int* total) {
    int lane = threadIdx.x & 63, wid = threadIdx.x >> 6;
    int iv = wave_incl_scan(v);
    if (lane == 63) wsums[wid] = iv;
    __syncthreads();
    if (wid == 0) {
        int s = (lane < 16) ? wsums[lane] : 0;
        s = wave_incl_scan(s);
        if (lane < 16) wsums[lane] = s;
    }
    __syncthreads();
    int add = (wid > 0) ? wsums[wid - 1] : 0;
    int incl = iv + add;
    *total = wsums[15];
    __syncthreads();
    return incl;
}

// inline is64 detection: first wave ballots high-halves of first 16 i64 coords
__device__ __forceinline__ int block_is64(const int* c32, int* sh) {
    if (threadIdx.x < 64) {
        unsigned long long b = __ballot(c32[2 * threadIdx.x + 1] != 0);
        if (threadIdx.x == 0) *sh = (b == 0ULL) ? 1 : 0;
    }
    __syncthreads();
    return *sh;
}

// count same-key earlier-thread entries in a padded LDS list (uint4 sweep)
__device__ __forceinline__ int list_rank(const u32* list, int lcount, u32 key, int t) {
    int local = 0;
    int L4 = (lcount + 3) >> 2;
    const uint4* l4 = (const uint4*)list;
    for (int p = 0; p < L4; p++) {
        uint4 e = l4[p];
        local += ((e.x & ~1023u) == key && (int)(e.x & 1023u) < t);
        local += ((e.y & ~1023u) == key && (int)(e.y & 1023u) < t);
        local += ((e.z & ~1023u) == key && (int)(e.z & 1023u) < t);
        local += ((e.w & ~1023u) == key && (int)(e.w & 1023u) < t);
    }
    return local;
}

// ---------------- kernels ----------------

// voxel blocks: window ids + in-window coords + u8-packed histogram of bwi0
// extra blocks (>= NB): build the 400x192 pe dictionary (bit-identical math)
__global__ __launch_bounds__(256) void k_wincoords(const void* coors_raw, int N, int NB,
        int CE4, int* bwi0, int* bwi1, int* ciw0, int* ciw1, u32* H0, float* dict) {
    __shared__ int s64;
    if ((int)blockIdx.x >= NB) {
        int e = ((int)blockIdx.x - NB) * 256 + (int)threadIdx.x;
        if (e < 76800) {
            int idx = e / 192;
            int j = e - idx * 192;
            int dz = idx & 3;
            int dy = (idx >> 2) % 10;
            int dx = (idx >> 2) / 10;
            int sel = j >> 6;
            float v = (sel == 0) ? ((float)dx - 5.0f)
                    : ((sel == 1) ? ((float)dy - 5.0f) : ((float)dz - 2.0f));
            int kk = (j & 63) >> 1;
            float invf = (float)exp(6.907755278982137 * (double)kk / 32.0);  // 1000^(kk/32)
            float a = v / invf;
            dict[e] = (j & 1) ? cosf(a) : sinf(a);
        }
        return;
    }
    int is64 = block_is64((const int*)coors_raw, &s64);
    int i = (int)blockIdx.x * 256 + (int)threadIdx.x;
    if (i >= N) return;
    int b, z, y, x;
    const i32x4* c4 = (const i32x4*)coors_raw;
    if (is64) {
        i32x4 q0 = c4[2 * (size_t)i];
        i32x4 q1 = c4[2 * (size_t)i + 1];
        b = q0.x; z = q0.z; y = q1.x; x = q1.z;   // little-endian low words
    } else {
        i32x4 q = c4[i];
        b = q.x; z = q.y; y = q.z; x = q.w;
    }
    int ch = i >> 10;
    {   // shift=false: shx=10, shy=10, shz=4
        int scx = x + 10, scy = y + 10, scz = z + 4;
        int w = b * MPER + (scx / 10) * 205 + (scy / 10) * 5 + (scz >> 2);
        bwi0[i] = w;
        ciw0[i] = (scz & 3) | ((scy % 10) << 8) | ((scx % 10) << 16);
        atomicAdd(&H0[(size_t)w * CE4 + (ch >> 2)], 1u << ((ch & 3) * 8));
    }
    {   // shift=true: shx=5, shy=5, shz=2
        int scx = x + 5, scy = y + 5, scz = z + 2;
        int w = b * MPER + (scx / 10) * 205 + (scy / 10) * 5 + (scz >> 2);
        bwi1[i] = w;
        ciw1[i] = (scz & 3) | ((scy % 10) << 8) | ((scx % 10) << 16);
    }
}

// wave-per-window exclusive prefix over u8-packed chunk quads (in-place, saturate 255)
// counts[w] = window total (saturate 1023). Extra blocks (>= PB): vec4 fill of rowvox.
__global__ __launch_bounds__(256) void k_prefix8(u32* H, u16* counts, int CE4, int NW,
                                                 int PB, int* fillPtr, int fillN4) {
    if ((int)blockIdx.x >= PB) {
        int idx = ((int)blockIdx.x - PB) * 256 + (int)threadIdx.x;
        if (idx < fillN4) {
            i32x4 v = (i32x4){-1, -1, -1, -1};
            __builtin_nontemporal_store(v, ((i32x4*)fillPtr) + idx);
        }
        return;
    }
    int w = ((int)blockIdx.x * 256 + (int)threadIdx.x) >> 6;
    int lane = threadIdx.x & 63;
    if (w >= NW) return;
    u32* row = H + (size_t)w * CE4;
    int run = 0;
    for (int p0 = 0; p0 < CE4; p0 += 64) {
        int p = p0 + lane;
        u32 v = (p < CE4) ? row[p] : 0u;
        int b0 = (int)(v & 255u), b1 = (int)((v >> 8) & 255u);
        int b2 = (int)((v >> 16) & 255u), b3 = (int)(v >> 24);
        int s = b0 + b1 + b2 + b3;
        int incl = wave_incl_scan(s);
        int base = run + incl - s;
        int e0 = base, e1 = base + b0, e2 = e1 + b1, e3 = e2 + b2;
        u32 o0 = (u32)(e0 > 255 ? 255 : e0);
        u32 o1 = (u32)(e1 > 255 ? 255 : e1);
        u32 o2 = (u32)(e2 > 255 ? 255 : e2);
        u32 o3 = (u32)(e3 > 255 ? 255 : e3);
        if (p < CE4) row[p] = o0 | (o1 << 8) | (o2 << 16) | (o3 << 24);
        run += __shfl(incl, 63, 64);
        if (run > 1023) run = 1023;
    }
    if (lane == 0) counts[w] = (u16)run;
}

// stage1: inner rank in bwi0 via collider-list -> km0 bitmask; u8 histogram of bwi1 over kept
__global__ __launch_bounds__(1024) void k_stage1(const int* bwi0, const int* bwi1,
        const u16* counts0, const u8* H0b, u32* H1, u64* km0, int N, int CB, int CE4) {
    __shared__ alignas(16) u32 list[1028];
    __shared__ int lcount;
    int c = blockIdx.x, t = threadIdx.x, lane = t & 63, wv = t >> 6;
    int i = (c << 10) + t;
    if (t == 0) lcount = 0;
    __syncthreads();
    int w0 = -1, cur = 0, cnt = 0;
    if (i < N) {
        w0 = bwi0[i];
        size_t ro = (size_t)w0 * CB + c;
        cur = (int)H0b[ro];
        int nxt = (c + 1 < CB) ? (int)H0b[ro + 1] : (int)counts0[w0];
        cnt = nxt - cur;
        if (cnt >= 2) { int p = atomicAdd(&lcount, 1); list[p] = ((u32)w0 << 10) | (u32)t; }
    }
    __syncthreads();
    if (t < 3) list[lcount + t] = 0xFFFFFFFFu;
    __syncthreads();
    int k0 = 0;
    if (i < N) {
        int local = (cnt >= 2) ? list_rank(list, lcount, (u32)w0 << 10, t) : 0;
        k0 = (cur + local) < target_of(level_of((int)counts0[w0]));
    }
    u64 bal = __ballot(k0);
    if (lane == 0) km0[((size_t)c << 4) + wv] = bal;
    if (k0) atomicAdd(&H1[(size_t)bwi1[i] * CE4 + (c >> 2)], 1u << ((c & 3) * 8));
}

// stage2: inner rank in bwi1 among keep0 -> kmf bitmask; u8 final histograms + chunk counts
__global__ __launch_bounds__(1024) void k_stage2(const int* bwi0, const int* bwi1,
        const u64* km0, const u16* counts1k, const u8* H1b,
        u32* HF0, u32* HF1, u64* kmf, int* chunkcnt, int N, int CB, int CE4) {
    __shared__ alignas(16) u32 list[1028];
    __shared__ int lcount, blksum;
    int c = blockIdx.x, t = threadIdx.x, lane = t & 63, wv = t >> 6;
    int i = (c << 10) + t;
    int k0 = (int)((km0[((size_t)c << 4) + wv] >> lane) & 1ULL);
    if (t == 0) { lcount = 0; blksum = 0; }
    __syncthreads();
    int w1 = -1, cur = 0, cnt = 0;
    if (k0) {
        w1 = bwi1[i];
        size_t ro = (size_t)w1 * CB + c;
        cur = (int)H1b[ro];
        int nxt = (c + 1 < CB) ? (int)H1b[ro + 1] : (int)counts1k[w1];
        cnt = nxt - cur;
        if (cnt >= 2) { int p = atomicAdd(&lcount, 1); list[p] = ((u32)w1 << 10) | (u32)t; }
    }
    __syncthreads();
    if (t < 3) list[lcount + t] = 0xFFFFFFFFu;
    __syncthreads();
    int kf = 0;
    if (k0) {
        int local = (cnt >= 2) ? list_rank(list, lcount, (u32)w1 << 10, t) : 0;
        kf = (cur + local) < target_of(level_of((int)counts1k[w1]));
    }
    u64 bal = __ballot(kf);
    if (lane == 0) {
        kmf[((size_t)c << 4) + wv] = bal;
        atomicAdd(&blksum, __popcll(bal));
    }
    if (kf) {
        atomicAdd(&HF0[(size_t)bwi0[i] * CE4 + (c >> 2)], 1u << ((c & 3) * 8));
        atomicAdd(&HF1[(size_t)w1 * CE4 + (c >> 2)], 1u << ((c & 3) * 8));
    }
    __syncthreads();
    if (t == 0) chunkcnt[c] = blksum;
}

// fused: block 0 = chunk-count scan (-> NKEPT); blocks 1,2 = conti for shift 0/1
__global__ __launch_bounds__(1024) void k_midscan(int* chunkcnt, int C, int* meta,
        const u16* counts0, const u16* fcount0, int* conti0,
        const u16* counts1, const u16* fcount1, int* conti1) {
    __shared__ int wsums[16];
    __shared__ int running;
    __shared__ int run3[3];
    if (blockIdx.x == 0) {
        if (threadIdx.x == 0) running = 0;
        __syncthreads();
        for (int base = 0; base < C; base += 1024) {
            int i = base + threadIdx.x;
            int v = (i < C) ? chunkcnt[i] : 0;
            int total;
            int incl = block_incl_scan_1024(v, wsums, &total);
            int run = running;
            if (i < C) chunkcnt[i] = run + incl - v;
            __syncthreads();
            if (threadIdx.x == 0) running = run + total;
            __syncthreads();
        }
        if (threadIdx.x == 0) meta[M_NKEPT] = running;
    } else {
        const u16* counts = (blockIdx.x == 2) ? counts1 : counts0;
        const u16* fcount = (blockIdx.x == 2) ? fcount1 : fcount0;
        int* conti = (blockIdx.x == 2) ? conti1 : conti0;
        int* nwin_out = meta + ((blockIdx.x == 2) ? M_NWIN1 : M_NWIN0);
        if (threadIdx.x < 3) run3[threadIdx.x] = 0;
        __syncthreads();
        for (int base = 0; base < WTOT; base += 1024) {
            int i = base + threadIdx.x;
            int c = (i < WTOT) ? (int)counts[i] : 0;
            int f = (i < WTOT) ? (int)fcount[i] : 0;
            int lvl = level_of(c);
            int act = (c > 0 && f > 0) ? 1 : 0;
            int packed = act ? (1 << (11 * lvl)) : 0;
            int total;
            int incl = block_incl_scan_1024(packed, wsums, &total);
            int excl = incl - packed;
            int r0 = run3[0], r1 = run3[1], r2 = run3[2];
            if (i < WTOT) {
                int e;
                if (lvl == 0) e = r0 + (excl & 2047);
                else if (lvl == 1) e = r1 + ((excl >> 11) & 2047);
                else e = r2 + ((excl >> 22) & 2047);
                conti[i] = e;
            }
            __syncthreads();
            if (threadIdx.x == 0) {
                run3[0] = r0 + (total & 2047);
                run3[1] = r1 + ((total >> 11) & 2047);
                run3[2] = r2 + ((total >> 22) & 2047);
            }
            __syncthreads();
        }
        if (threadIdx.x < 3) nwin_out[threadIdx.x] = run3[threadIdx.x];
    }
}

// stage3: final inner ranks via collider-lists + mask-based compaction + row->ciw scatter
__global__ __launch_bounds__(1024) void k_stage3(const int* bwi0, const int* bwi1,
        const int* ciw0, const int* ciw1, const u64* kmf,
        const u16* counts0, const u16* counts1k,
        const int* conti0, const int* conti1,
        const u8* HF0b, const u8* HF1b,
        const u16* fcount0, const u16* fcount1,
        const int* chunkpref, const int* meta,
        int* idxarr, int* rowvox0, int* rowvox1, int N, int CB) {
    __shared__ alignas(16) u32 list0[1028];
    __shared__ alignas(16) u32 list1[1028];
    __shared__ int lc0, lc1, wsum[16];
    int c = blockIdx.x, t = threadIdx.x, lane = t & 63, wv = t >> 6;
    int i = (c << 10) + t;
    if (t == 0) { lc0 = 0; lc1 = 0; }
    u64 m = kmf[((size_t)c << 4) + wv];
    int kf = (int)((m >> lane) & 1ULL);
    if (lane == 0) wsum[wv] = __popcll(m);
    __syncthreads();
    if (t < 64) {
        int s = (t < 16) ? wsum[t] : 0;
        s = wave_incl_scan(s);
        if (t < 16) wsum[t] = s;
    }
    __syncthreads();
    int lk = (wv ? wsum[wv - 1] : 0) + __popcll(m & ((1ull << lane) - 1ull));
    int w0 = -1, w1 = -1, cur0 = 0, cur1 = 0, cnt0 = 0, cnt1 = 0;
    if (kf) {
        w0 = bwi0[i]; w1 = bwi1[i];
        size_t r0o = (size_t)w0 * CB + c;
        cur0 = (int)HF0b[r0o];
        int nxt0 = (c + 1 < CB) ? (int)HF0b[r0o + 1] : (int)fcount0[w0];
        cnt0 = nxt0 - cur0;
        if (cnt0 >= 2) { int p = atomicAdd(&lc0, 1); list0[p] = ((u32)w0 << 10) | (u32)t; }
        size_t r1o = (size_t)w1 * CB + c;
        cur1 = (int)HF1b[r1o];
        int nxt1 = (c + 1 < CB) ? (int)HF1b[r1o + 1] : (int)fcount1[w1];
        cnt1 = nxt1 - cur1;
        if (cnt1 >= 2) { int p = atomicAdd(&lc1, 1); list1[p] = ((u32)w1 << 10) | (u32)t; }
    }
    __syncthreads();
    if (t < 3) { list0[lc0 + t] = 0xFFFFFFFFu; list1[lc1 + t] = 0xFFFFFFFFu; }
    __syncthreads();
    if (!kf) return;
    int l0 = (cnt0 >= 2) ? list_rank(list0, lc0, (u32)w0 << 10, t) : 0;
    int l1 = (cnt1 >= 2) ? list_rank(list1, lc1, (u32)w1 << 10, t) : 0;
    int innerF0 = cur0 + l0;
    int innerF1 = cur1 + l1;
    idxarr[chunkpref[c] + lk] = i;
    int n00 = meta[M_NWIN0], n01 = meta[M_NWIN0 + 1];
    int n10 = meta[M_NWIN1], n11 = meta[M_NWIN1 + 1];
    {
        int lvl = level_of((int)counts0[w0]);
        int T = target_of(lvl);
        int rb = (lvl == 0) ? 0 : ((lvl == 1) ? n00 * 16 : (n00 * 16 + n01 * 32));
        rowvox0[rb + conti0[w0] * T + innerF0] = ciw0[i];
    }
    {
        int lvl = level_of((int)counts1k[w1]);
        int T = target_of(lvl);
        int rb = (lvl == 0) ? 0 : ((lvl == 1) ? n10 * 16 : (n10 * 16 + n11 * 32));
        rowvox1[rb + conti1[w1] * T + innerF1] = ciw1[i];
    }
}

// fused render: blocks [0,NA) gather feats+coords; blocks [NA,grid) write pe+masks
// bulk output via non-temporal stores; feats read via non-temporal loads (read-once)
__global__ __launch_bounds__(256) void k_render(const float* feats, const void* coors_raw,
        const int* meta, const int* idxarr, const int* rowvox0, const int* rowvox1,
        const float* dict, float* out, int NA) {
    __shared__ int s64;
    int nk = meta[M_NKEPT];
    int n00 = meta[M_NWIN0], n01 = meta[M_NWIN0 + 1], n02 = meta[M_NWIN0 + 2];
    int n10 = meta[M_NWIN1], n11 = meta[M_NWIN1 + 1], n12 = meta[M_NWIN1 + 2];
    int R0 = n00 * 16 + n01 * 32 + n02 * 48;
    int R1 = n10 * 16 + n11 * 32 + n12 * 48;
    int obuf0 = nk * 196;            // nk*192 feats + nk*4 coords
    int omask0 = obuf0 + R0 * 192;
    int obuf1 = omask0 + R0;
    int omask1 = obuf1 + R1 * 192;
    int ototal = omask1 + R1;
    if ((int)blockIdx.x < NA) {
        int is64 = block_is64((const int*)coors_raw, &s64);
        int ocoor = nk * 192;
        const f32x4* src = (const f32x4*)feats;
        f32x4* dst = (f32x4*)out;
        int tot = nk * 52;           // nk*48 feat-float4s + nk*4 coord scalars
        int step = NA * 256;
        for (int idx = (int)blockIdx.x * 256 + (int)threadIdx.x; idx < tot; idx += step) {
            if (idx < nk * 48) {
                int row = idx / 48;
                int col = idx - row * 48;
                f32x4 v = __builtin_nontemporal_load(src + (size_t)idxarr[row] * 48 + col);
                __builtin_nontemporal_store(v, dst + idx);
            } else {
                int cidx = idx - nk * 48;
                int k = cidx >> 2, tt = cidx & 3;
                int ii = idxarr[k];
                int v = is64 ? (int)((const long long*)coors_raw)[4LL * ii + tt]
                             : ((const int*)coors_raw)[4 * ii + tt];
                out[ocoor + cidx] = (float)v;
            }
        }
    } else {
        int q0 = obuf0 >> 2, q1 = ototal >> 2;
        const f32x4* dict4 = (const f32x4*)dict;
        f32x4* out4 = (f32x4*)out;
        int step = ((int)gridDim.x - NA) * 256;
        for (int q = q0 + ((int)blockIdx.x - NA) * 256 + (int)threadIdx.x; q < q1; q += step) {
            int e = q << 2;
            f32x4 val;
            bool pe1 = (e >= obuf1) && (e < omask1);
            if ((e < omask0) || pe1) {
                unsigned rel = (unsigned)(e - (pe1 ? obuf1 : obuf0));
                unsigned row = rel / 192u;
                unsigned j = rel - row * 192u;
                int ciw = pe1 ? rowvox1[row] : rowvox0[row];
                if (ciw < 0) {
                    val = (f32x4){0.0f, 0.0f, 0.0f, 0.0f};
                } else {
                    int di = (ciw & 3) + ((ciw >> 8) & 15) * 4 + ((ciw >> 16) & 15) * 40;
                    val = dict4[di * 48 + (int)(j >> 2)];
                }
            } else {
                int base = (e >= omask1) ? omask1 : omask0;
                const int* rv = (e >= omask1) ? rowvox1 : rowvox0;
                const i32x4 c4 = *(const i32x4*)(rv + (e - base));
                val.x = (c4.x < 0) ? 1.0f : 0.0f;
                val.y = (c4.y < 0) ? 1.0f : 0.0f;
                val.z = (c4.z < 0) ? 1.0f : 0.0f;
                val.w = (c4.w < 0) ? 1.0f : 0.0f;
            }
            __builtin_nontemporal_store(val, out4 + q);
        }
    }
}

// ---------------- host launch ----------------
extern "C" void kernel_launch(void* const* d_in, const int* in_sizes, int n_in,
                              void* d_out, int out_size, void* d_ws, size_t ws_size,
                              hipStream_t stream) {
    const float* feats = (const float*)d_in[0];
    const void* coors = d_in[1];
    int N = in_sizes[0] / 192;
    int C = (N + 1023) >> 10;
    int CE4 = (C + 3) >> 2;             // u32 words per table row (4 u8 cells each)
    int CB = CE4 * 4;                   // bytes per table row
    size_t TW = (size_t)WTOT * CE4;     // u32 words per table
    int N4 = (N + 3) & ~3;

    int* bwi0 = (int*)d_ws;         int* bwi1 = bwi0 + N4;
    int* ciw0 = bwi1 + N4;          int* ciw1 = ciw0 + N4;
    int* idxarr = ciw1 + N4;
    u64* km0 = (u64*)(idxarr + N4);             // C*16 u64 wave-ballot words
    u64* kmf = km0 + (size_t)C * 16;
    u32* H0 = (u32*)(kmf + (size_t)C * 16);     // 4 u8-packed tables, contiguous
    u32* H1 = H0 + TW;
    u32* HF0 = H1 + TW;
    u32* HF1 = HF0 + TW;
    u16* counts0 = (u16*)(HF1 + TW);            // u16[WTOT], padded to 8408 words
    u16* counts1k = (u16*)((u32*)counts0 + 8408);
    u16* fcount0 = (u16*)((u32*)counts1k + 8408);  // u16[2*WTOT] contiguous (dual prefix)
    u16* fcount1 = fcount0 + WTOT;
    int* chunkcnt = (int*)((u32*)fcount0 + 16812);
    int CP4 = (C + 3) & ~3;
    int* conti0 = chunkcnt + CP4;
    int* conti1 = conti0 + 16812;
    int* rowvox0 = conti1 + 16812;
    int* rowvox1 = rowvox0 + MAXROWS;
    int* meta = rowvox1 + MAXROWS;
    float* dict = (float*)(meta + M_WORDS);     // 400*192 floats

    int nb256 = (N + 255) / 256;

    (void)hipMemsetAsync(H0, 0, 4 * TW * sizeof(u32), stream);

    k_wincoords<<<nb256 + 300, 256, 0, stream>>>(coors, N, nb256, CE4,
                                                 bwi0, bwi1, ciw0, ciw1, H0, dict);

    int pgrid = (WTOT + 3) / 4;     // 4 window-waves per 256-thread block
    k_prefix8<<<pgrid, 256, 0, stream>>>(H0, counts0, CE4, WTOT, pgrid, (int*)0, 0);
    k_stage1<<<C, 1024, 0, stream>>>(bwi0, bwi1, counts0, (const u8*)H0, H1, km0, N, CB, CE4);

    k_prefix8<<<pgrid, 256, 0, stream>>>(H1, counts1k, CE4, WTOT, pgrid, (int*)0, 0);
    k_stage2<<<C, 1024, 0, stream>>>(bwi0, bwi1, km0, counts1k, (const u8*)H1,
                                     HF0, HF1, kmf, chunkcnt, N, CB, CE4);

    // HF0/HF1 rows contiguous: one dual prefix pass; extra blocks -1-fill rowvox for stage3
    int pgridF = (2 * WTOT + 3) / 4;
    int fillN4 = (2 * MAXROWS) / 4;
    int fillB = (fillN4 + 255) / 256;
    k_prefix8<<<pgridF + fillB, 256, 0, stream>>>(HF0, fcount0, CE4, 2 * WTOT,
                                                  pgridF, rowvox0, fillN4);
    k_midscan<<<3, 1024, 0, stream>>>(chunkcnt, C, meta,
                                      counts0, fcount0, conti0,
                                      counts1k, fcount1, conti1);

    k_stage3<<<C, 1024, 0, stream>>>(bwi0, bwi1, ciw0, ciw1, kmf, counts0, counts1k,
                                     conti0, conti1, (const u8*)HF0, (const u8*)HF1,
                                     fcount0, fcount1, chunkcnt, meta,
                                     idxarr, rowvox0, rowvox1, N, CB);

    k_render<<<4096, 256, 0, stream>>>(feats, coors, meta, idxarr, rowvox0, rowvox1,
                                       dict, (float*)d_out, 1536);

    (void)n_in; (void)ws_size; (void)out_size;
}